// Round 4
// baseline (390.660 us; speedup 1.0000x reference)
//
#include <hip/hip_runtime.h>
#include <hip/hip_fp16.h>

// VQ codebook quantization, MI355X.
//   prep:   fp32->bf16 fragment repack + norms + all zero-inits (no memsets).
//   passA:  round-0 proven structure: bf16 MFMA 32x32x16, 2Mx2N frags/wave,
//           A-frags resident in registers, B 64-row tiles staged in LDS
//           (2x32KB dbuf, global_load_lds). Epilogue: per 16-code window emit
//           u32 = fp16(min) | mask16 of codes within win_min+EPS.
//   passB12: per-row min over fp16 window-mins + EPS select; expand candidate
//           windows' mask16 to per-CODE entries in LDS; 16-lane groups rescore
//           exact fp32 (2 KB/entry) + atomicMin64. Row-chunked x2 (tm u32).
//   passB34: 2048 blocks, wave per 2 rows (32 waves/CU): gather quantized rows
//           + indices + counts. Loss comes FREE from winner's high 32 bits
//           (bd == ||z-e||^2 exactly as rescored) -- no z reads, no loss VALU.
//           Ticket block reduces lossarr+counts -> losses/perplexity.
// B=8192, d_latent=512, ncb=2, K=8192, d_sub=256.

#define KCODES 8192
#define DSUB   256
#define BROWS  8192
#define NROWS  16384
#define NWIN   512

#define QUANT_N  (BROWS * 512)
#define IDX_OFF  QUANT_N
#define LOSS_OFF (QUANT_N + NROWS)

// ws layout (bytes)
#define WS_ESQ     0          // 16384 f32
#define WS_ZSQ     65536      // 16384 f32
#define WS_COUNTS  131072     // 16384 i32   (zeroed in prep)
#define WS_WINNER  196608     // 16384 u64   (0xFF.. in prep)
#define WS_LOSSARR 327680     // 2048 f32    (one slot per B34 block)
#define WS_TICK    335872     // 1 u32       (zeroed in prep; ticket for B34)
#define WS_ZBF     1048576    // [2][8192][256] bf16 = 8 MB, fragment layout
#define WS_EBF     9437184    // [2][8192][256] bf16 = 8 MB, fragment layout
#define WS_TM      17825792   // [2][4096][512] u32 = 16 MB (ONE row-chunk)

#define EPS 2.5e-4f

// Fragment layout (elements, per codebook): row r, element k ->
//   (r>>4)*4096 + (k>>5)*512 + ((k>>3)&3)*128 + (r&15)*8 + (k&7)
// 32x32x16 view: lane (l5,c32) reads short8 at
//   (grp + (c32>>4))*4096 + (k0>>1)*512 + (k0&1)*256 + l5*128 + (lane&15)*8.

typedef __attribute__((ext_vector_type(8))) short short8;
typedef __attribute__((ext_vector_type(8))) unsigned short ushort8v;
typedef __attribute__((ext_vector_type(16))) float floatx16;

__device__ inline void gl2lds16(const void* g, void* l) {
  __builtin_amdgcn_global_load_lds(
      (const __attribute__((address_space(1))) void*)g,
      (__attribute__((address_space(3))) void*)l, 16, 0, 0);
}

__device__ inline unsigned short f2bf(float f) {
  unsigned u = __float_as_uint(f);
  return (unsigned short)((u + 0x7FFFu + ((u >> 16) & 1u)) >> 16);
}

__device__ inline int agent_load_i(const int* p) {
  return __hip_atomic_load(p, __ATOMIC_RELAXED, __HIP_MEMORY_SCOPE_AGENT);
}
__device__ inline float agent_load_f(const float* p) {
  return __hip_atomic_load(p, __ATOMIC_RELAXED, __HIP_MEMORY_SCOPE_AGENT);
}
__device__ inline void agent_store_f(float* p, float v) {
  __hip_atomic_store(p, v, __ATOMIC_RELAXED, __HIP_MEMORY_SCOPE_AGENT);
}

// ------------------------------------------------------------ prep kernel
__global__ void prep_kernel(const float* __restrict__ z, const float* __restrict__ e,
                            float* __restrict__ e_sq, float* __restrict__ z_sq,
                            unsigned short* __restrict__ zbf, unsigned short* __restrict__ ebf,
                            int* __restrict__ counts, unsigned long long* __restrict__ winner,
                            unsigned* __restrict__ tick, float* __restrict__ lossarr) {
  int t = blockIdx.x * 256 + threadIdx.x;
  if (t < 16384) { counts[t] = 0; winner[t] = ~0ull; }
  if (t < 2048) lossarr[t] = 0.0f;
  if (t == 16384) *tick = 0;

  int gw  = blockIdx.x * 4 + (threadIdx.x >> 6);  // 0..4095
  int l   = threadIdx.x & 63;
  int sub = l >> 5;
  int l32 = l & 31;
  for (int i = 0; i < 4; ++i) {
    int row = i * 8192 + gw * 2 + sub;            // 0..32767 (i<2: emb, else z)
    const float* src;
    unsigned short* dst;
    int r;
    float* sq;
    int sqi;
    if (row < NROWS) {
      src = e + (size_t)row * DSUB;
      dst = ebf; r = row; sq = e_sq; sqi = row;
    } else {
      int rz = row - NROWS;
      int n = rz & 1, b = rz >> 1;
      src = z + (size_t)rz * DSUB;
      dst = zbf + (size_t)n * 2097152; r = b; sq = z_sq; sqi = rz;
    }
    float4 v0 = ((const float4*)src)[2 * l32];
    float4 v1 = ((const float4*)src)[2 * l32 + 1];
    ushort8v o;
    o[0] = f2bf(v0.x); o[1] = f2bf(v0.y); o[2] = f2bf(v0.z); o[3] = f2bf(v0.w);
    o[4] = f2bf(v1.x); o[5] = f2bf(v1.y); o[6] = f2bf(v1.z); o[7] = f2bf(v1.w);
    size_t off = (size_t)(r >> 4) * 4096 + (l32 >> 2) * 512 + (l32 & 3) * 128 + (r & 15) * 8;
    *(ushort8v*)(dst + off) = o;
    float s = v0.x * v0.x + v0.y * v0.y + v0.z * v0.z + v0.w * v0.w
            + v1.x * v1.x + v1.y * v1.y + v1.z * v1.z + v1.w * v1.w;
    #pragma unroll
    for (int off2 = 16; off2; off2 >>= 1) s += __shfl_down(s, off2, 32);
    if (l32 == 0) sq[sqi] = s;
  }
}

// ------------------------------------------------------------ pass A (MFMA)
// Grid (32, 8, 2) per chunk, 256 threads. Block = 256 codes x 512 rows (8 nt
// of 64). Wave: 64 codes (2 M-frags, A resident in reg) x 64 rows (2 N-frags,
// B from LDS, 2x32KB dbuf via global_load_lds). Proven 48% MfmaUtil structure.
__global__ __launch_bounds__(256, 2)
void passA_kernel(const unsigned short* __restrict__ zbf, const unsigned short* __restrict__ ebf,
                  const float* __restrict__ e_sq, unsigned* __restrict__ tm32, int rowoff) {
  __shared__ unsigned short Bs[2][16384];         // 2 x 32KB

  const int n    = blockIdx.z;
  const int tid  = threadIdx.x;
  const int w    = tid >> 6, lane = tid & 63;
  const int l5   = lane >> 5, c32 = lane & 31;
  const int cb   = blockIdx.x * 256 + w * 64;
  const int rg   = rowoff + blockIdx.y * 512;

  const unsigned short* en = ebf + (size_t)n * 2097152;
  const unsigned short* zn = zbf + (size_t)n * 2097152;
  const float* esq = e_sq + n * KCODES;
  unsigned* tmn = tm32 + (size_t)n * (4096 * NWIN);

  // lane-constant fragment address part (elements)
  const int lo = (c32 >> 4) * 4096 + l5 * 128 + (lane & 15) * 8;

  // A fragments: 2 M-frags x 16 k-steps, short8 each (128 VGPR)
  short8 areg[16][2];
  #pragma unroll
  for (int k0 = 0; k0 < 16; ++k0)
    #pragma unroll
    for (int mi = 0; mi < 2; ++mi)
      areg[k0][mi] = *(const short8*)(en + (size_t)((cb >> 4) + mi * 2) * 4096
                                      + (k0 >> 1) * 512 + (k0 & 1) * 256 + lo);

  // e_sq per acc reg: code = cb + mi*32 + (reg&3) + 8*(reg>>2) + 4*l5
  float eq[2][16];
  #pragma unroll
  for (int mi = 0; mi < 2; ++mi)
    #pragma unroll
    for (int reg = 0; reg < 16; ++reg)
      eq[mi][reg] = esq[cb + mi * 32 + (reg & 3) + 8 * (reg >> 2) + 4 * l5];

  // stage first 32KB B tile
  const unsigned short* zg = zn + (size_t)(rg >> 4) * 4096;
  {
    const int eo = w * 512 + lane * 8;
    #pragma unroll
    for (int i = 0; i < 8; ++i)
      gl2lds16(zg + i * 2048 + eo, &Bs[0][i * 2048 + w * 512]);
  }

  for (int nt = 0; nt < 8; ++nt) {
    __syncthreads();            // staged buffer ready; prev buffer readers done
    if (nt < 7) {
      const unsigned short* zs = zg + (nt + 1) * 16384;
      unsigned short* ld = &Bs[(nt + 1) & 1][0];
      const int eo = w * 512 + lane * 8;
      #pragma unroll
      for (int i = 0; i < 8; ++i)
        gl2lds16(zs + i * 2048 + eo, ld + i * 2048 + w * 512);
    }
    const unsigned short* bsrc = &Bs[nt & 1][0];
    const int rowbase = rg + nt * 64;

    floatx16 acc[2][2];
    #pragma unroll
    for (int mi = 0; mi < 2; ++mi)
      #pragma unroll
      for (int nf = 0; nf < 2; ++nf)
        #pragma unroll
        for (int i = 0; i < 16; ++i) acc[mi][nf][i] = 0.f;

    #pragma unroll
    for (int k0 = 0; k0 < 16; ++k0) {
      const int ko = (k0 >> 1) * 512 + (k0 & 1) * 256 + lo;
      short8 b0 = *(const short8*)&bsrc[ko];
      short8 b1 = *(const short8*)&bsrc[8192 + ko];
      acc[0][0] = __builtin_amdgcn_mfma_f32_32x32x16_bf16(areg[k0][0], b0, acc[0][0], 0, 0, 0);
      acc[0][1] = __builtin_amdgcn_mfma_f32_32x32x16_bf16(areg[k0][0], b1, acc[0][1], 0, 0, 0);
      acc[1][0] = __builtin_amdgcn_mfma_f32_32x32x16_bf16(areg[k0][1], b0, acc[1][0], 0, 0, 0);
      acc[1][1] = __builtin_amdgcn_mfma_f32_32x32x16_bf16(areg[k0][1], b1, acc[1][1], 0, 0, 0);
    }

    // epilogue: 4 windows of 16 codes; per window fp16(min) | mask16(<=min+EPS)
    #pragma unroll
    for (int nf = 0; nf < 2; ++nf) {
      unsigned wd[4];
      #pragma unroll
      for (int mi = 0; mi < 2; ++mi) {
        float va[16];
        #pragma unroll
        for (int r = 0; r < 16; ++r) va[r] = eq[mi][r] - 2.0f * acc[mi][nf][r];
        float m0 = va[0], m1 = va[8];
        #pragma unroll
        for (int r = 1; r < 8; ++r) { m0 = fminf(m0, va[r]); m1 = fminf(m1, va[r + 8]); }
        m0 = fminf(m0, __shfl_xor(m0, 32, 64));
        m1 = fminf(m1, __shfl_xor(m1, 32, 64));
        const float t0 = m0 + EPS, t1 = m1 + EPS;
        unsigned k0m = 0, k1m = 0;
        #pragma unroll
        for (int r = 0; r < 8; ++r) {
          const int bp = (r & 3) + 8 * (r >> 2) + 4 * l5;
          k0m |= (unsigned)(va[r] <= t0) << bp;
          k1m |= (unsigned)(va[r + 8] <= t1) << bp;
        }
        k0m |= (unsigned)__shfl_xor((int)k0m, 32, 64);
        k1m |= (unsigned)__shfl_xor((int)k1m, 32, 64);
        wd[mi * 2]     = (unsigned)__half_as_ushort(__float2half(m0)) | (k0m << 16);
        wd[mi * 2 + 1] = (unsigned)__half_as_ushort(__float2half(m1)) | (k1m << 16);
      }
      if (l5 == 0) {
        int zr = rowbase + nf * 32 + c32;
        uint4 o; o.x = wd[0]; o.y = wd[1]; o.z = wd[2]; o.w = wd[3];
        *(uint4*)&tmn[(size_t)(zr - rowoff) * NWIN + (cb >> 4)] = o;
      }
    }
  }
}

// ------------------------------------------------------------ passB12 (select+rescore)
// Phase 1 (per wave, 8 rows): row min over fp16 window-mins + EPS select;
// expand candidate windows' mask16 to per-CODE entries in LDS.
// Phase 2: 16-lane groups rescore entries exact fp32 (1 KB emb + 1 KB z each).
__global__ __launch_bounds__(256)
void passB12_kernel(const unsigned* __restrict__ tm32, const float* __restrict__ z,
                    const float* __restrict__ emb, const float* __restrict__ e_sq,
                    const float* __restrict__ z_sq,
                    unsigned long long* __restrict__ winner, int rzoff) {
  __shared__ unsigned buf[4][512];
  __shared__ unsigned wcnt[4];
  __shared__ unsigned pre[5];

  const int w = threadIdx.x >> 6, lane = threadIdx.x & 63;
  const int gw = blockIdx.x * 4 + w;
  const int r0 = rzoff + gw * 8;                  // global z-row (rz) base
  const int boff = rzoff >> 1;                    // chunk-local codebook-row base

  uint4 ta[8], tb[8];
  #pragma unroll
  for (int i = 0; i < 8; ++i) {
    int rz = r0 + i;
    int nn = rz & 1, b = rz >> 1;
    const unsigned* p = tm32 + ((size_t)nn * 4096 + (b - boff)) * NWIN + lane * 8;
    ta[i] = *(const uint4*)p;
    tb[i] = *(const uint4*)(p + 4);
  }

  unsigned cnt = 0;
  #pragma unroll
  for (int i = 0; i < 8; ++i) {
    const int rz = r0 + i;
    unsigned wv[8] = {ta[i].x, ta[i].y, ta[i].z, ta[i].w, tb[i].x, tb[i].y, tb[i].z, tb[i].w};
    float v[8];
    #pragma unroll
    for (int j = 0; j < 8; ++j)
      v[j] = __half2float(__ushort_as_half((unsigned short)(wv[j] & 0xFFFFu)));
    float mv = v[0];
    #pragma unroll
    for (int j = 1; j < 8; ++j) mv = fminf(mv, v[j]);
    #pragma unroll
    for (int off = 32; off; off >>= 1) mv = fminf(mv, __shfl_xor(mv, off, 64));
    const float thr = mv + EPS;
    #pragma unroll
    for (int j = 0; j < 8; ++j) {
      unsigned long long mb = __ballot(v[j] <= thr);
      while (mb) {
        int src = __ffsll(mb) - 1;
        mb &= mb - 1;
        unsigned word = (unsigned)__shfl((int)wv[j], src, 64);
        unsigned msk = word >> 16;
        int win = src * 8 + j;
        while (msk) {
          int bit = __ffs(msk) - 1;
          msk &= msk - 1;
          if (cnt < 512) {
            if (lane == 0) buf[w][cnt] = ((unsigned)rz << 13) | (unsigned)(win * 16 + bit);
            ++cnt;
          }
        }
      }
    }
  }
  if (lane == 0) wcnt[w] = cnt;
  __syncthreads();
  if (threadIdx.x == 0) {
    unsigned s = 0;
    #pragma unroll
    for (int i = 0; i < 4; ++i) { pre[i] = s; s += wcnt[i]; }
    pre[4] = s;
  }
  __syncthreads();

  const unsigned total = pre[4];
  const int g = lane >> 4, l16 = lane & 15;
  for (unsigned i0 = 0; i0 < total; i0 += 16) {
    unsigned idx = i0 + (unsigned)(w * 4 + g);
    if (idx < total) {
      int bkt = 0;
      while (bkt < 3 && idx >= pre[bkt + 1]) ++bkt;
      unsigned e = buf[bkt][idx - pre[bkt]];
      int rz = (int)(e >> 13), code = (int)(e & 8191u), nn = rz & 1;
      const float4* ep = (const float4*)(emb + ((size_t)nn * KCODES + code) * DSUB);
      const float4* zp = (const float4*)(z + (size_t)rz * DSUB);
      float s = 0.f;
      #pragma unroll
      for (int u = 0; u < 4; ++u) {
        float4 ev = ep[l16 + 16 * u];
        float4 zv = zp[l16 + 16 * u];
        s += ev.x * zv.x; s += ev.y * zv.y; s += ev.z * zv.z; s += ev.w * zv.w;
      }
      s += __shfl_xor(s, 1, 64);
      s += __shfl_xor(s, 2, 64);
      s += __shfl_xor(s, 4, 64);
      s += __shfl_xor(s, 8, 64);
      if (l16 == 0) {
        float bd = (z_sq[rz] - 2.0f * s) + e_sq[nn * KCODES + code];
        atomicMin(&winner[rz],
                  ((unsigned long long)__float_as_uint(bd) << 32) | (unsigned)code);
      }
    }
  }
}

// ------------------------------------------------------------ passB34 (gather+final)
// 2048 blocks x 256 thr; wave handles 2 rows (one even cb0, one odd cb1).
// 32 waves/CU; single gather round -> latency fully hidden. Loss comes from
// winner's high 32 bits (exact rescored fp32 distance) -- no z traffic.
__global__ __launch_bounds__(256)
void passB34_kernel(const float* __restrict__ emb,
                    const unsigned long long* __restrict__ winner, float* __restrict__ out,
                    int* __restrict__ counts, float* __restrict__ lossarr,
                    unsigned* __restrict__ ticket) {
  __shared__ float lsum[4];
  __shared__ unsigned lastflag;
  const int w = threadIdx.x >> 6, lane = threadIdx.x & 63;
  const int gw = blockIdx.x * 4 + w;        // 0..8191
  const int row0 = gw * 2;                  // even -> codebook 0; +1 -> codebook 1

  unsigned long long w0 = winner[row0];
  unsigned long long w1 = winner[row0 + 1];
  int bk0 = (int)(unsigned)w0;
  int bk1 = (int)(unsigned)w1;
  const float* eb0 = emb + (size_t)bk0 * DSUB;
  const float* eb1 = emb + ((size_t)KCODES + bk1) * DSUB;
  float4 ev0 = ((const float4*)eb0)[lane];
  float4 ev1 = ((const float4*)eb1)[lane];
  ((float4*)(out + (size_t)row0 * DSUB))[lane] = ev0;
  ((float4*)(out + (size_t)(row0 + 1) * DSUB))[lane] = ev1;
  if (lane == 0) {
    out[IDX_OFF + row0]     = (float)bk0;
    out[IDX_OFF + row0 + 1] = (float)bk1;
    atomicAdd(&counts[bk0], 1);
    atomicAdd(&counts[KCODES + bk1], 1);
    lsum[w] = __uint_as_float((unsigned)(w0 >> 32)) + __uint_as_float((unsigned)(w1 >> 32));
  }
  __syncthreads();
  if (threadIdx.x == 0)
    agent_store_f(&lossarr[blockIdx.x], lsum[0] + lsum[1] + lsum[2] + lsum[3]);

  // ---- ticket: last block reduces counts + loss (fused final) ----
  __threadfence();
  __syncthreads();
  if (threadIdx.x == 0) lastflag = atomicAdd(ticket, 1);
  __syncthreads();
  if (lastflag != gridDim.x - 1) return;
  __threadfence();

  __shared__ float redh[256];
  __shared__ float redl[256];
  float h = 0.0f, ls = 0.0f;
  for (int k = threadIdx.x; k < KCODES; k += 256) {
    float c0 = (float)agent_load_i(&counts[k]);
    float c1 = (float)agent_load_i(&counts[KCODES + k]);
    float p = (c0 + c1) * (1.0f / 16384.0f);
    h -= p * logf(p + 1e-10f);
  }
  for (int k = threadIdx.x; k < 2048; k += 256) ls += agent_load_f(&lossarr[k]);
  redh[threadIdx.x] = h;
  redl[threadIdx.x] = ls;
  __syncthreads();
  for (int s = 128; s; s >>= 1) {
    if (threadIdx.x < s) {
      redh[threadIdx.x] += redh[threadIdx.x + s];
      redl[threadIdx.x] += redl[threadIdx.x + s];
    }
    __syncthreads();
  }
  if (threadIdx.x == 0) {
    out[LOSS_OFF + 0] = 0.25f * redl[0] * (1.0f / (float)QUANT_N);
    out[LOSS_OFF + 1] = 0.0f;
    out[LOSS_OFF + 2] = expf(redh[0]);
  }
}

extern "C" void kernel_launch(void* const* d_in, const int* in_sizes, int n_in,
                              void* d_out, int out_size, void* d_ws, size_t ws_size,
                              hipStream_t stream) {
  const float* z   = (const float*)d_in[0];
  const float* emb = (const float*)d_in[1];
  float* out = (float*)d_out;
  char*  ws  = (char*)d_ws;

  float* e_sq   = (float*)(ws + WS_ESQ);
  float* z_sq   = (float*)(ws + WS_ZSQ);
  int*   counts = (int*)(ws + WS_COUNTS);
  unsigned long long* winner = (unsigned long long*)(ws + WS_WINNER);
  float* lossarr = (float*)(ws + WS_LOSSARR);
  unsigned* tick = (unsigned*)(ws + WS_TICK);
  unsigned short* zbf = (unsigned short*)(ws + WS_ZBF);
  unsigned short* ebf = (unsigned short*)(ws + WS_EBF);
  unsigned* tm32 = (unsigned*)(ws + WS_TM);

  prep_kernel<<<1024, 256, 0, stream>>>(z, emb, e_sq, z_sq, zbf, ebf, counts, winner, tick, lossarr);
  for (int c = 0; c < 2; ++c) {
    dim3 gA(32, 8, 2);
    passA_kernel<<<gA, 256, 0, stream>>>(zbf, ebf, e_sq, tm32, c * 4096);
    passB12_kernel<<<256, 256, 0, stream>>>(tm32, z, emb, e_sq, z_sq, winner, c * 8192);
  }
  passB34_kernel<<<2048, 256, 0, stream>>>(emb, winner, out, counts, lossarr, tick);
}

// Round 5
// 204.646 us; speedup vs baseline: 1.9090x; 1.9090x over previous
//
#include <hip/hip_runtime.h>
#include <hip/hip_fp16.h>

// VQ codebook quantization, MI355X.
//   prep:   fp32->bf16 fragment repack + norms + all zero-inits (no memsets).
//   passA:  bf16 MFMA 32x32x16, 2Mx2N frags/wave, A-frags resident in regs,
//           B 64-row tiles in LDS (2x32KB dbuf, global_load_lds), depth-1
//           B-register prefetch inside the k-loop (overlap ds_read with MFMA).
//           Epilogue: per 16-code window u32 = fp16(min) | mask16(<=min+EPS).
//   passB12: per-row min over fp16 window-mins + EPS select; expand candidate
//           windows' mask16 to per-CODE entries in LDS; 16-lane groups rescore
//           exact fp32 (2 KB/entry) + atomicMin64. Row-chunked x2 (tm u32).
//   passB3: 1024 blocks, wave per 4 rows (ILP-4): gather quantized rows +
//           indices + counts; loss free from winner high bits. NO fence/ticket.
//   final:  separate 1-block kernel (kernel boundary = coherence): losses +
//           perplexity.
// B=8192, d_latent=512, ncb=2, K=8192, d_sub=256.

#define KCODES 8192
#define DSUB   256
#define BROWS  8192
#define NROWS  16384
#define NWIN   512

#define QUANT_N  (BROWS * 512)
#define IDX_OFF  QUANT_N
#define LOSS_OFF (QUANT_N + NROWS)

// ws layout (bytes)
#define WS_ESQ     0          // 16384 f32
#define WS_ZSQ     65536      // 16384 f32
#define WS_COUNTS  131072     // 16384 i32   (zeroed in prep)
#define WS_WINNER  196608     // 16384 u64   (0xFF.. in prep)
#define WS_LOSSARR 327680     // 1024 f32    (every slot written by passB3)
#define WS_ZBF     1048576    // [2][8192][256] bf16 = 8 MB, fragment layout
#define WS_EBF     9437184    // [2][8192][256] bf16 = 8 MB, fragment layout
#define WS_TM      17825792   // [2][4096][512] u32 = 16 MB (ONE row-chunk)

#define EPS 2.5e-4f

// Fragment layout (elements, per codebook): row r, element k ->
//   (r>>4)*4096 + (k>>5)*512 + ((k>>3)&3)*128 + (r&15)*8 + (k&7)
// 32x32x16 view: lane (l5,c32) reads short8 at
//   (grp + (c32>>4))*4096 + (k0>>1)*512 + (k0&1)*256 + l5*128 + (lane&15)*8.

typedef __attribute__((ext_vector_type(8))) short short8;
typedef __attribute__((ext_vector_type(8))) unsigned short ushort8v;
typedef __attribute__((ext_vector_type(16))) float floatx16;

__device__ inline void gl2lds16(const void* g, void* l) {
  __builtin_amdgcn_global_load_lds(
      (const __attribute__((address_space(1))) void*)g,
      (__attribute__((address_space(3))) void*)l, 16, 0, 0);
}

__device__ inline unsigned short f2bf(float f) {
  unsigned u = __float_as_uint(f);
  return (unsigned short)((u + 0x7FFFu + ((u >> 16) & 1u)) >> 16);
}

// ------------------------------------------------------------ prep kernel
__global__ void prep_kernel(const float* __restrict__ z, const float* __restrict__ e,
                            float* __restrict__ e_sq, float* __restrict__ z_sq,
                            unsigned short* __restrict__ zbf, unsigned short* __restrict__ ebf,
                            int* __restrict__ counts, unsigned long long* __restrict__ winner) {
  int t = blockIdx.x * 256 + threadIdx.x;
  if (t < 16384) { counts[t] = 0; winner[t] = ~0ull; }

  int gw  = blockIdx.x * 4 + (threadIdx.x >> 6);  // 0..4095
  int l   = threadIdx.x & 63;
  int sub = l >> 5;
  int l32 = l & 31;
  for (int i = 0; i < 4; ++i) {
    int row = i * 8192 + gw * 2 + sub;            // 0..32767 (i<2: emb, else z)
    const float* src;
    unsigned short* dst;
    int r;
    float* sq;
    int sqi;
    if (row < NROWS) {
      src = e + (size_t)row * DSUB;
      dst = ebf; r = row; sq = e_sq; sqi = row;
    } else {
      int rz = row - NROWS;
      int n = rz & 1, b = rz >> 1;
      src = z + (size_t)rz * DSUB;
      dst = zbf + (size_t)n * 2097152; r = b; sq = z_sq; sqi = rz;
    }
    float4 v0 = ((const float4*)src)[2 * l32];
    float4 v1 = ((const float4*)src)[2 * l32 + 1];
    ushort8v o;
    o[0] = f2bf(v0.x); o[1] = f2bf(v0.y); o[2] = f2bf(v0.z); o[3] = f2bf(v0.w);
    o[4] = f2bf(v1.x); o[5] = f2bf(v1.y); o[6] = f2bf(v1.z); o[7] = f2bf(v1.w);
    size_t off = (size_t)(r >> 4) * 4096 + (l32 >> 2) * 512 + (l32 & 3) * 128 + (r & 15) * 8;
    *(ushort8v*)(dst + off) = o;
    float s = v0.x * v0.x + v0.y * v0.y + v0.z * v0.z + v0.w * v0.w
            + v1.x * v1.x + v1.y * v1.y + v1.z * v1.z + v1.w * v1.w;
    #pragma unroll
    for (int off2 = 16; off2; off2 >>= 1) s += __shfl_down(s, off2, 32);
    if (l32 == 0) sq[sqi] = s;
  }
}

// ------------------------------------------------------------ pass A (MFMA)
// Grid (32, 8, 2) per chunk, 256 threads. Block = 256 codes x 512 rows (8 nt
// of 64). Wave: 64 codes (2 M-frags, A resident) x 64 rows (2 N-frags, B from
// LDS dbuf). Depth-1 B prefetch: ds_read k0+1 issues before k0's MFMAs.
__global__ __launch_bounds__(256, 2)
void passA_kernel(const unsigned short* __restrict__ zbf, const unsigned short* __restrict__ ebf,
                  const float* __restrict__ e_sq, unsigned* __restrict__ tm32, int rowoff) {
  __shared__ unsigned short Bs[2][16384];         // 2 x 32KB

  const int n    = blockIdx.z;
  const int tid  = threadIdx.x;
  const int w    = tid >> 6, lane = tid & 63;
  const int l5   = lane >> 5, c32 = lane & 31;
  const int cb   = blockIdx.x * 256 + w * 64;
  const int rg   = rowoff + blockIdx.y * 512;

  const unsigned short* en = ebf + (size_t)n * 2097152;
  const unsigned short* zn = zbf + (size_t)n * 2097152;
  const float* esq = e_sq + n * KCODES;
  unsigned* tmn = tm32 + (size_t)n * (4096 * NWIN);

  // lane-constant fragment address part (elements)
  const int lo = (c32 >> 4) * 4096 + l5 * 128 + (lane & 15) * 8;

  // A fragments: 2 M-frags x 16 k-steps, short8 each (128 VGPR)
  short8 areg[16][2];
  #pragma unroll
  for (int k0 = 0; k0 < 16; ++k0)
    #pragma unroll
    for (int mi = 0; mi < 2; ++mi)
      areg[k0][mi] = *(const short8*)(en + (size_t)((cb >> 4) + mi * 2) * 4096
                                      + (k0 >> 1) * 512 + (k0 & 1) * 256 + lo);

  // e_sq per acc reg: code = cb + mi*32 + (reg&3) + 8*(reg>>2) + 4*l5
  float eq[2][16];
  #pragma unroll
  for (int mi = 0; mi < 2; ++mi)
    #pragma unroll
    for (int reg = 0; reg < 16; ++reg)
      eq[mi][reg] = esq[cb + mi * 32 + (reg & 3) + 8 * (reg >> 2) + 4 * l5];

  // stage first 32KB B tile
  const unsigned short* zg = zn + (size_t)(rg >> 4) * 4096;
  {
    const int eo = w * 512 + lane * 8;
    #pragma unroll
    for (int i = 0; i < 8; ++i)
      gl2lds16(zg + i * 2048 + eo, &Bs[0][i * 2048 + w * 512]);
  }

  for (int nt = 0; nt < 8; ++nt) {
    __syncthreads();            // staged buffer ready; prev buffer readers done
    if (nt < 7) {
      const unsigned short* zs = zg + (nt + 1) * 16384;
      unsigned short* ld = &Bs[(nt + 1) & 1][0];
      const int eo = w * 512 + lane * 8;
      #pragma unroll
      for (int i = 0; i < 8; ++i)
        gl2lds16(zs + i * 2048 + eo, ld + i * 2048 + w * 512);
    }
    const unsigned short* bsrc = &Bs[nt & 1][0];
    const int rowbase = rg + nt * 64;

    floatx16 acc[2][2];
    #pragma unroll
    for (int mi = 0; mi < 2; ++mi)
      #pragma unroll
      for (int nf = 0; nf < 2; ++nf)
        #pragma unroll
        for (int i = 0; i < 16; ++i) acc[mi][nf][i] = 0.f;

    short8 b0 = *(const short8*)&bsrc[lo];
    short8 b1 = *(const short8*)&bsrc[8192 + lo];
    #pragma unroll
    for (int k0 = 0; k0 < 16; ++k0) {
      short8 n0 = b0, n1 = b1;
      if (k0 < 15) {
        const int kn = ((k0 + 1) >> 1) * 512 + ((k0 + 1) & 1) * 256 + lo;
        n0 = *(const short8*)&bsrc[kn];
        n1 = *(const short8*)&bsrc[8192 + kn];
      }
      acc[0][0] = __builtin_amdgcn_mfma_f32_32x32x16_bf16(areg[k0][0], b0, acc[0][0], 0, 0, 0);
      acc[0][1] = __builtin_amdgcn_mfma_f32_32x32x16_bf16(areg[k0][0], b1, acc[0][1], 0, 0, 0);
      acc[1][0] = __builtin_amdgcn_mfma_f32_32x32x16_bf16(areg[k0][1], b0, acc[1][0], 0, 0, 0);
      acc[1][1] = __builtin_amdgcn_mfma_f32_32x32x16_bf16(areg[k0][1], b1, acc[1][1], 0, 0, 0);
      b0 = n0; b1 = n1;
    }

    // epilogue: 4 windows of 16 codes; per window fp16(min) | mask16(<=min+EPS)
    #pragma unroll
    for (int nf = 0; nf < 2; ++nf) {
      unsigned wd[4];
      #pragma unroll
      for (int mi = 0; mi < 2; ++mi) {
        float va[16];
        #pragma unroll
        for (int r = 0; r < 16; ++r) va[r] = eq[mi][r] - 2.0f * acc[mi][nf][r];
        float m0 = va[0], m1 = va[8];
        #pragma unroll
        for (int r = 1; r < 8; ++r) { m0 = fminf(m0, va[r]); m1 = fminf(m1, va[r + 8]); }
        m0 = fminf(m0, __shfl_xor(m0, 32, 64));
        m1 = fminf(m1, __shfl_xor(m1, 32, 64));
        const float t0 = m0 + EPS, t1 = m1 + EPS;
        unsigned k0m = 0, k1m = 0;
        #pragma unroll
        for (int r = 0; r < 8; ++r) {
          const int bp = (r & 3) + 8 * (r >> 2) + 4 * l5;
          k0m |= (unsigned)(va[r] <= t0) << bp;
          k1m |= (unsigned)(va[r + 8] <= t1) << bp;
        }
        k0m |= (unsigned)__shfl_xor((int)k0m, 32, 64);
        k1m |= (unsigned)__shfl_xor((int)k1m, 32, 64);
        wd[mi * 2]     = (unsigned)__half_as_ushort(__float2half(m0)) | (k0m << 16);
        wd[mi * 2 + 1] = (unsigned)__half_as_ushort(__float2half(m1)) | (k1m << 16);
      }
      if (l5 == 0) {
        int zr = rowbase + nf * 32 + c32;
        uint4 o; o.x = wd[0]; o.y = wd[1]; o.z = wd[2]; o.w = wd[3];
        *(uint4*)&tmn[(size_t)(zr - rowoff) * NWIN + (cb >> 4)] = o;
      }
    }
  }
}

// ------------------------------------------------------------ passB12 (select+rescore)
// Phase 1 (per wave, 8 rows): row min over fp16 window-mins + EPS select;
// expand candidate windows' mask16 to per-CODE entries in LDS.
// Phase 2: 16-lane groups rescore entries exact fp32 (1 KB emb + 1 KB z each).
__global__ __launch_bounds__(256)
void passB12_kernel(const unsigned* __restrict__ tm32, const float* __restrict__ z,
                    const float* __restrict__ emb, const float* __restrict__ e_sq,
                    const float* __restrict__ z_sq,
                    unsigned long long* __restrict__ winner, int rzoff) {
  __shared__ unsigned buf[4][512];
  __shared__ unsigned wcnt[4];
  __shared__ unsigned pre[5];

  const int w = threadIdx.x >> 6, lane = threadIdx.x & 63;
  const int gw = blockIdx.x * 4 + w;
  const int r0 = rzoff + gw * 8;                  // global z-row (rz) base
  const int boff = rzoff >> 1;                    // chunk-local codebook-row base

  uint4 ta[8], tb[8];
  #pragma unroll
  for (int i = 0; i < 8; ++i) {
    int rz = r0 + i;
    int nn = rz & 1, b = rz >> 1;
    const unsigned* p = tm32 + ((size_t)nn * 4096 + (b - boff)) * NWIN + lane * 8;
    ta[i] = *(const uint4*)p;
    tb[i] = *(const uint4*)(p + 4);
  }

  unsigned cnt = 0;
  #pragma unroll
  for (int i = 0; i < 8; ++i) {
    const int rz = r0 + i;
    unsigned wv[8] = {ta[i].x, ta[i].y, ta[i].z, ta[i].w, tb[i].x, tb[i].y, tb[i].z, tb[i].w};
    float v[8];
    #pragma unroll
    for (int j = 0; j < 8; ++j)
      v[j] = __half2float(__ushort_as_half((unsigned short)(wv[j] & 0xFFFFu)));
    float mv = v[0];
    #pragma unroll
    for (int j = 1; j < 8; ++j) mv = fminf(mv, v[j]);
    #pragma unroll
    for (int off = 32; off; off >>= 1) mv = fminf(mv, __shfl_xor(mv, off, 64));
    const float thr = mv + EPS;
    #pragma unroll
    for (int j = 0; j < 8; ++j) {
      unsigned long long mb = __ballot(v[j] <= thr);
      while (mb) {
        int src = __ffsll(mb) - 1;
        mb &= mb - 1;
        unsigned word = (unsigned)__shfl((int)wv[j], src, 64);
        unsigned msk = word >> 16;
        int win = src * 8 + j;
        while (msk) {
          int bit = __ffs(msk) - 1;
          msk &= msk - 1;
          if (cnt < 512) {
            if (lane == 0) buf[w][cnt] = ((unsigned)rz << 13) | (unsigned)(win * 16 + bit);
            ++cnt;
          }
        }
      }
    }
  }
  if (lane == 0) wcnt[w] = cnt;
  __syncthreads();
  if (threadIdx.x == 0) {
    unsigned s = 0;
    #pragma unroll
    for (int i = 0; i < 4; ++i) { pre[i] = s; s += wcnt[i]; }
    pre[4] = s;
  }
  __syncthreads();

  const unsigned total = pre[4];
  const int g = lane >> 4, l16 = lane & 15;
  for (unsigned i0 = 0; i0 < total; i0 += 16) {
    unsigned idx = i0 + (unsigned)(w * 4 + g);
    if (idx < total) {
      int bkt = 0;
      while (bkt < 3 && idx >= pre[bkt + 1]) ++bkt;
      unsigned e = buf[bkt][idx - pre[bkt]];
      int rz = (int)(e >> 13), code = (int)(e & 8191u), nn = rz & 1;
      const float4* ep = (const float4*)(emb + ((size_t)nn * KCODES + code) * DSUB);
      const float4* zp = (const float4*)(z + (size_t)rz * DSUB);
      float s = 0.f;
      #pragma unroll
      for (int u = 0; u < 4; ++u) {
        float4 ev = ep[l16 + 16 * u];
        float4 zv = zp[l16 + 16 * u];
        s += ev.x * zv.x; s += ev.y * zv.y; s += ev.z * zv.z; s += ev.w * zv.w;
      }
      s += __shfl_xor(s, 1, 64);
      s += __shfl_xor(s, 2, 64);
      s += __shfl_xor(s, 4, 64);
      s += __shfl_xor(s, 8, 64);
      if (l16 == 0) {
        float bd = (z_sq[rz] - 2.0f * s) + e_sq[nn * KCODES + code];
        atomicMin(&winner[rz],
                  ((unsigned long long)__float_as_uint(bd) << 32) | (unsigned)code);
      }
    }
  }
}

// ------------------------------------------------------------ passB3 (gather)
// 1024 blocks x 256 thr; wave per 4 rows (ILP-4 chains; 16 waves/CU).
// Loss free from winner's high 32 bits (exact rescored fp32 distance).
// NO fence, NO ticket -- final reduction is a separate kernel.
__global__ __launch_bounds__(256)
void passB3_kernel(const float* __restrict__ emb,
                   const unsigned long long* __restrict__ winner, float* __restrict__ out,
                   int* __restrict__ counts, float* __restrict__ lossarr) {
  __shared__ float lsum[4];
  const int w = threadIdx.x >> 6, lane = threadIdx.x & 63;
  const int gw = blockIdx.x * 4 + w;        // 0..4095
  const int r0 = gw * 4;

  unsigned long long wv[4];
  #pragma unroll
  for (int i = 0; i < 4; ++i) wv[i] = winner[r0 + i];

  float4 ev[4];
  #pragma unroll
  for (int i = 0; i < 4; ++i) {
    int bk = (int)(unsigned)wv[i];
    ev[i] = ((const float4*)(emb + ((size_t)((r0 + i) & 1) * KCODES + bk) * DSUB))[lane];
  }
  #pragma unroll
  for (int i = 0; i < 4; ++i)
    ((float4*)(out + (size_t)(r0 + i) * DSUB))[lane] = ev[i];

  if (lane < 4) {
    int bk = (int)(unsigned)wv[lane];
    out[IDX_OFF + r0 + lane] = (float)bk;
    atomicAdd(&counts[((r0 + lane) & 1) * KCODES + bk], 1);
  }
  if (lane == 0) {
    float ls = 0.f;
    #pragma unroll
    for (int i = 0; i < 4; ++i) ls += __uint_as_float((unsigned)(wv[i] >> 32));
    lsum[w] = ls;
  }
  __syncthreads();
  if (threadIdx.x == 0)
    lossarr[blockIdx.x] = lsum[0] + lsum[1] + lsum[2] + lsum[3];
}

// ------------------------------------------------------------ final kernel
__global__ void final_kernel(const int* __restrict__ counts, const float* __restrict__ lossarr,
                             float* __restrict__ out) {
  __shared__ float redh[256];
  __shared__ float redl[256];
  float h = 0.0f, ls = 0.0f;
  for (int k = threadIdx.x; k < KCODES; k += 256) {
    float p = (float)(counts[k] + counts[KCODES + k]) * (1.0f / 16384.0f);
    h -= p * logf(p + 1e-10f);
  }
  for (int k = threadIdx.x; k < 1024; k += 256) ls += lossarr[k];
  redh[threadIdx.x] = h;
  redl[threadIdx.x] = ls;
  __syncthreads();
  for (int s = 128; s; s >>= 1) {
    if (threadIdx.x < s) {
      redh[threadIdx.x] += redh[threadIdx.x + s];
      redl[threadIdx.x] += redl[threadIdx.x + s];
    }
    __syncthreads();
  }
  if (threadIdx.x == 0) {
    out[LOSS_OFF + 0] = 0.25f * redl[0] * (1.0f / (float)QUANT_N);
    out[LOSS_OFF + 1] = 0.0f;
    out[LOSS_OFF + 2] = expf(redh[0]);
  }
}

extern "C" void kernel_launch(void* const* d_in, const int* in_sizes, int n_in,
                              void* d_out, int out_size, void* d_ws, size_t ws_size,
                              hipStream_t stream) {
  const float* z   = (const float*)d_in[0];
  const float* emb = (const float*)d_in[1];
  float* out = (float*)d_out;
  char*  ws  = (char*)d_ws;

  float* e_sq   = (float*)(ws + WS_ESQ);
  float* z_sq   = (float*)(ws + WS_ZSQ);
  int*   counts = (int*)(ws + WS_COUNTS);
  unsigned long long* winner = (unsigned long long*)(ws + WS_WINNER);
  float* lossarr = (float*)(ws + WS_LOSSARR);
  unsigned short* zbf = (unsigned short*)(ws + WS_ZBF);
  unsigned short* ebf = (unsigned short*)(ws + WS_EBF);
  unsigned* tm32 = (unsigned*)(ws + WS_TM);

  prep_kernel<<<1024, 256, 0, stream>>>(z, emb, e_sq, z_sq, zbf, ebf, counts, winner);
  for (int c = 0; c < 2; ++c) {
    dim3 gA(32, 8, 2);
    passA_kernel<<<gA, 256, 0, stream>>>(zbf, ebf, e_sq, tm32, c * 4096);
    passB12_kernel<<<256, 256, 0, stream>>>(tm32, z, emb, e_sq, z_sq, winner, c * 8192);
  }
  passB3_kernel<<<1024, 256, 0, stream>>>(emb, winner, out, counts, lossarr);
  final_kernel<<<1, 256, 0, stream>>>(counts, lossarr, out);
}

// Round 6
// 195.469 us; speedup vs baseline: 1.9986x; 1.0470x over previous
//
#include <hip/hip_runtime.h>
#include <hip/hip_fp16.h>

// VQ codebook quantization, MI355X.
//   prep:   wave-per-16-row-group repack: fully coalesced 1KB fragment-group
//           stores (old version scattered 16B at 256B stride), norms via shfl.
//   passA:  bf16 MFMA 32x32x16, 2Mx2N frags/wave, A-frags resident in regs,
//           B 64-row tiles in LDS (2x32KB dbuf, global_load_lds). Plain k-loop
//           (round-3 form; explicit register prefetch measurably regressed).
//           Epilogue: per 16-code window u32 = fp16(min) | mask16(<=min+EPS).
//   passB12: 2 rows/wave, 1024 blocks/chunk (4 waves/SIMD): row min + EPS
//           select, expand mask16 to per-code entries (per-wave list); 16-lane
//           groups rescore exact fp32 (2 KB/entry) + atomicMin64. Chunked x2.
//   passB3: 1024 blocks, wave per 4 rows: gather quantized + indices + counts;
//           loss free from winner high bits. No fence/ticket.
//   final:  separate 1-block kernel: losses + perplexity.
// B=8192, d_latent=512, ncb=2, K=8192, d_sub=256.

#define KCODES 8192
#define DSUB   256
#define BROWS  8192
#define NROWS  16384
#define NWIN   512

#define QUANT_N  (BROWS * 512)
#define IDX_OFF  QUANT_N
#define LOSS_OFF (QUANT_N + NROWS)

// ws layout (bytes)
#define WS_ESQ     0          // 16384 f32
#define WS_ZSQ     65536      // 16384 f32
#define WS_COUNTS  131072     // 16384 i32   (zeroed in prep)
#define WS_WINNER  196608     // 16384 u64   (0xFF.. in prep)
#define WS_LOSSARR 327680     // 1024 f32    (every slot written by passB3)
#define WS_ZBF     1048576    // [2][8192][256] bf16 = 8 MB, fragment layout
#define WS_EBF     9437184    // [2][8192][256] bf16 = 8 MB, fragment layout
#define WS_TM      17825792   // [2][4096][512] u32 = 16 MB (ONE row-chunk)

#define EPS 2.5e-4f

// Fragment layout (elements, per codebook): row r, element k ->
//   (r>>4)*4096 + (k>>5)*512 + ((k>>3)&3)*128 + (r&15)*8 + (k&7)
// 32x32x16 view: lane (l5,c32) reads short8 at
//   (grp + (c32>>4))*4096 + (k0>>1)*512 + (k0&1)*256 + l5*128 + (lane&15)*8.
// prep identity: group-local offset for (r16, k=c4*8+j*32) = j*512 + lane*8
//   with lane = c4*16 + r16  -> wave store at j*512+lane*8 is 1KB contiguous.

typedef __attribute__((ext_vector_type(8))) short short8;
typedef __attribute__((ext_vector_type(8))) unsigned short ushort8v;
typedef __attribute__((ext_vector_type(16))) float floatx16;

__device__ inline void gl2lds16(const void* g, void* l) {
  __builtin_amdgcn_global_load_lds(
      (const __attribute__((address_space(1))) void*)g,
      (__attribute__((address_space(3))) void*)l, 16, 0, 0);
}

__device__ inline unsigned short f2bf(float f) {
  unsigned u = __float_as_uint(f);
  return (unsigned short)((u + 0x7FFFu + ((u >> 16) & 1u)) >> 16);
}

// ------------------------------------------------------------ prep kernel
// 512 blocks x 256. Wave gi handles one 16-row fragment group (8KB):
//   lane l: row r16 = l&15, col slot c4 = l>>4; iter j: cols c4*8+j*32..+8.
//   Store: group_base + j*512 + l*8 elems -> 1KB contiguous per wave-instr.
__global__ __launch_bounds__(256)
void prep_kernel(const float* __restrict__ z, const float* __restrict__ e,
                 float* __restrict__ e_sq, float* __restrict__ z_sq,
                 unsigned short* __restrict__ zbf, unsigned short* __restrict__ ebf,
                 int* __restrict__ counts, unsigned long long* __restrict__ winner) {
  int t = blockIdx.x * 256 + threadIdx.x;
  if (t < 16384) { counts[t] = 0; winner[t] = ~0ull; }

  const int w = threadIdx.x >> 6, lane = threadIdx.x & 63;
  const int gi = blockIdx.x * 4 + w;              // 0..2047
  const int r16 = lane & 15, c4 = lane >> 4;

  const float* srcrow;
  unsigned short* dstg;
  if (gi < 1024) {                                // emb groups: rows gi*16..+16
    srcrow = e + (size_t)(gi * 16 + r16) * DSUB;
    dstg   = ebf + (size_t)gi * 4096;
  } else {                                        // z groups: (n, g2)
    int g2n = gi - 1024;
    int n = g2n & 1, g2 = g2n >> 1;               // g2 in [0,512)
    int rz = 2 * (g2 * 16 + r16) + n;
    srcrow = z + (size_t)rz * DSUB;
    dstg   = zbf + (size_t)n * 2097152 + (size_t)g2 * 4096;
  }

  float ssq = 0.f;
  #pragma unroll
  for (int j = 0; j < 8; ++j) {
    const int col = c4 * 8 + j * 32;
    float4 v0 = *(const float4*)(srcrow + col);
    float4 v1 = *(const float4*)(srcrow + col + 4);
    ushort8v o;
    o[0] = f2bf(v0.x); o[1] = f2bf(v0.y); o[2] = f2bf(v0.z); o[3] = f2bf(v0.w);
    o[4] = f2bf(v1.x); o[5] = f2bf(v1.y); o[6] = f2bf(v1.z); o[7] = f2bf(v1.w);
    *(ushort8v*)(dstg + j * 512 + lane * 8) = o;
    ssq += v0.x * v0.x + v0.y * v0.y + v0.z * v0.z + v0.w * v0.w
         + v1.x * v1.x + v1.y * v1.y + v1.z * v1.z + v1.w * v1.w;
  }
  ssq += __shfl_xor(ssq, 16, 64);
  ssq += __shfl_xor(ssq, 32, 64);
  if (lane < 16) {
    if (gi < 1024) {
      e_sq[gi * 16 + lane];
      e_sq[gi * 16 + lane] = ssq;
    } else {
      int g2n = gi - 1024;
      int n = g2n & 1, g2 = g2n >> 1;
      z_sq[2 * (g2 * 16 + lane) + n] = ssq;
    }
  }
}

// ------------------------------------------------------------ pass A (MFMA)
// Grid (32, 8, 2) per chunk, 256 threads. Block = 256 codes x 512 rows (8 nt
// of 64). Wave: 64 codes (2 M-frags, A resident in reg) x 64 rows (2 N-frags,
// B from LDS, 2x32KB dbuf via global_load_lds). Proven 48% MfmaUtil structure.
__global__ __launch_bounds__(256, 2)
void passA_kernel(const unsigned short* __restrict__ zbf, const unsigned short* __restrict__ ebf,
                  const float* __restrict__ e_sq, unsigned* __restrict__ tm32, int rowoff) {
  __shared__ unsigned short Bs[2][16384];         // 2 x 32KB

  const int n    = blockIdx.z;
  const int tid  = threadIdx.x;
  const int w    = tid >> 6, lane = tid & 63;
  const int l5   = lane >> 5, c32 = lane & 31;
  const int cb   = blockIdx.x * 256 + w * 64;
  const int rg   = rowoff + blockIdx.y * 512;

  const unsigned short* en = ebf + (size_t)n * 2097152;
  const unsigned short* zn = zbf + (size_t)n * 2097152;
  const float* esq = e_sq + n * KCODES;
  unsigned* tmn = tm32 + (size_t)n * (4096 * NWIN);

  // lane-constant fragment address part (elements)
  const int lo = (c32 >> 4) * 4096 + l5 * 128 + (lane & 15) * 8;

  // A fragments: 2 M-frags x 16 k-steps, short8 each (128 VGPR)
  short8 areg[16][2];
  #pragma unroll
  for (int k0 = 0; k0 < 16; ++k0)
    #pragma unroll
    for (int mi = 0; mi < 2; ++mi)
      areg[k0][mi] = *(const short8*)(en + (size_t)((cb >> 4) + mi * 2) * 4096
                                      + (k0 >> 1) * 512 + (k0 & 1) * 256 + lo);

  // e_sq per acc reg: code = cb + mi*32 + (reg&3) + 8*(reg>>2) + 4*l5
  float eq[2][16];
  #pragma unroll
  for (int mi = 0; mi < 2; ++mi)
    #pragma unroll
    for (int reg = 0; reg < 16; ++reg)
      eq[mi][reg] = esq[cb + mi * 32 + (reg & 3) + 8 * (reg >> 2) + 4 * l5];

  // stage first 32KB B tile
  const unsigned short* zg = zn + (size_t)(rg >> 4) * 4096;
  {
    const int eo = w * 512 + lane * 8;
    #pragma unroll
    for (int i = 0; i < 8; ++i)
      gl2lds16(zg + i * 2048 + eo, &Bs[0][i * 2048 + w * 512]);
  }

  for (int nt = 0; nt < 8; ++nt) {
    __syncthreads();            // staged buffer ready; prev buffer readers done
    if (nt < 7) {
      const unsigned short* zs = zg + (nt + 1) * 16384;
      unsigned short* ld = &Bs[(nt + 1) & 1][0];
      const int eo = w * 512 + lane * 8;
      #pragma unroll
      for (int i = 0; i < 8; ++i)
        gl2lds16(zs + i * 2048 + eo, ld + i * 2048 + w * 512);
    }
    const unsigned short* bsrc = &Bs[nt & 1][0];
    const int rowbase = rg + nt * 64;

    floatx16 acc[2][2];
    #pragma unroll
    for (int mi = 0; mi < 2; ++mi)
      #pragma unroll
      for (int nf = 0; nf < 2; ++nf)
        #pragma unroll
        for (int i = 0; i < 16; ++i) acc[mi][nf][i] = 0.f;

    #pragma unroll
    for (int k0 = 0; k0 < 16; ++k0) {
      const int ko = (k0 >> 1) * 512 + (k0 & 1) * 256 + lo;
      short8 b0 = *(const short8*)&bsrc[ko];
      short8 b1 = *(const short8*)&bsrc[8192 + ko];
      acc[0][0] = __builtin_amdgcn_mfma_f32_32x32x16_bf16(areg[k0][0], b0, acc[0][0], 0, 0, 0);
      acc[0][1] = __builtin_amdgcn_mfma_f32_32x32x16_bf16(areg[k0][0], b1, acc[0][1], 0, 0, 0);
      acc[1][0] = __builtin_amdgcn_mfma_f32_32x32x16_bf16(areg[k0][1], b0, acc[1][0], 0, 0, 0);
      acc[1][1] = __builtin_amdgcn_mfma_f32_32x32x16_bf16(areg[k0][1], b1, acc[1][1], 0, 0, 0);
    }

    // epilogue: 4 windows of 16 codes; per window fp16(min) | mask16(<=min+EPS)
    #pragma unroll
    for (int nf = 0; nf < 2; ++nf) {
      unsigned wd[4];
      #pragma unroll
      for (int mi = 0; mi < 2; ++mi) {
        float va[16];
        #pragma unroll
        for (int r = 0; r < 16; ++r) va[r] = eq[mi][r] - 2.0f * acc[mi][nf][r];
        float m0 = va[0], m1 = va[8];
        #pragma unroll
        for (int r = 1; r < 8; ++r) { m0 = fminf(m0, va[r]); m1 = fminf(m1, va[r + 8]); }
        m0 = fminf(m0, __shfl_xor(m0, 32, 64));
        m1 = fminf(m1, __shfl_xor(m1, 32, 64));
        const float t0 = m0 + EPS, t1 = m1 + EPS;
        unsigned k0m = 0, k1m = 0;
        #pragma unroll
        for (int r = 0; r < 8; ++r) {
          const int bp = (r & 3) + 8 * (r >> 2) + 4 * l5;
          k0m |= (unsigned)(va[r] <= t0) << bp;
          k1m |= (unsigned)(va[r + 8] <= t1) << bp;
        }
        k0m |= (unsigned)__shfl_xor((int)k0m, 32, 64);
        k1m |= (unsigned)__shfl_xor((int)k1m, 32, 64);
        wd[mi * 2]     = (unsigned)__half_as_ushort(__float2half(m0)) | (k0m << 16);
        wd[mi * 2 + 1] = (unsigned)__half_as_ushort(__float2half(m1)) | (k1m << 16);
      }
      if (l5 == 0) {
        int zr = rowbase + nf * 32 + c32;
        uint4 o; o.x = wd[0]; o.y = wd[1]; o.z = wd[2]; o.w = wd[3];
        *(uint4*)&tmn[(size_t)(zr - rowoff) * NWIN + (cb >> 4)] = o;
      }
    }
  }
}

// ------------------------------------------------------------ passB12 (select+rescore)
// 1024 blocks/chunk, 2 rows/wave (4 blocks/CU = 4 waves/SIMD).
// Phase 1: per row: min over fp16 window-mins + EPS select; expand candidate
//          windows' mask16 to per-code entries in this wave's LDS list.
// Phase 2: wave's 4x16-lane groups rescore own list exact fp32 + atomicMin64.
__global__ __launch_bounds__(256)
void passB12_kernel(const unsigned* __restrict__ tm32, const float* __restrict__ z,
                    const float* __restrict__ emb, const float* __restrict__ e_sq,
                    const float* __restrict__ z_sq,
                    unsigned long long* __restrict__ winner, int rzoff) {
  __shared__ unsigned buf[4][128];

  const int w = threadIdx.x >> 6, lane = threadIdx.x & 63;
  const int gw = blockIdx.x * 4 + w;              // 0..4095 per chunk
  const int r0 = rzoff + gw * 2;                  // global z-row base
  const int boff = rzoff >> 1;                    // chunk-local cb-row base

  unsigned cnt = 0;
  #pragma unroll
  for (int i = 0; i < 2; ++i) {
    const int rz = r0 + i;
    const int nn = rz & 1, b = rz >> 1;
    const unsigned* p = tm32 + ((size_t)nn * 4096 + (b - boff)) * NWIN + lane * 8;
    uint4 ta = *(const uint4*)p;
    uint4 tb = *(const uint4*)(p + 4);
    unsigned wv[8] = {ta.x, ta.y, ta.z, ta.w, tb.x, tb.y, tb.z, tb.w};
    float v[8];
    #pragma unroll
    for (int j = 0; j < 8; ++j)
      v[j] = __half2float(__ushort_as_half((unsigned short)(wv[j] & 0xFFFFu)));
    float mv = v[0];
    #pragma unroll
    for (int j = 1; j < 8; ++j) mv = fminf(mv, v[j]);
    #pragma unroll
    for (int off = 32; off; off >>= 1) mv = fminf(mv, __shfl_xor(mv, off, 64));
    const float thr = mv + EPS;
    #pragma unroll
    for (int j = 0; j < 8; ++j) {
      unsigned long long mb = __ballot(v[j] <= thr);
      while (mb) {
        int src = __ffsll(mb) - 1;
        mb &= mb - 1;
        unsigned word = (unsigned)__shfl((int)wv[j], src, 64);
        unsigned msk = word >> 16;
        int win = src * 8 + j;
        while (msk) {
          int bit = __ffs(msk) - 1;
          msk &= msk - 1;
          if (cnt < 128) {
            if (lane == 0) buf[w][cnt] = ((unsigned)rz << 13) | (unsigned)(win * 16 + bit);
            ++cnt;
          }
        }
      }
    }
  }
  __syncthreads();                                // LDS visibility (wave-local lists)

  const int g = lane >> 4, l16 = lane & 15;
  for (unsigned idx = (unsigned)g; idx < cnt; idx += 4) {
    unsigned e = buf[w][idx];
    int rz = (int)(e >> 13), code = (int)(e & 8191u), nn = rz & 1;
    const float4* ep = (const float4*)(emb + ((size_t)nn * KCODES + code) * DSUB);
    const float4* zp = (const float4*)(z + (size_t)rz * DSUB);
    float s = 0.f;
    #pragma unroll
    for (int u = 0; u < 4; ++u) {
      float4 ev = ep[l16 + 16 * u];
      float4 zv = zp[l16 + 16 * u];
      s += ev.x * zv.x; s += ev.y * zv.y; s += ev.z * zv.z; s += ev.w * zv.w;
    }
    s += __shfl_xor(s, 1, 64);
    s += __shfl_xor(s, 2, 64);
    s += __shfl_xor(s, 4, 64);
    s += __shfl_xor(s, 8, 64);
    if (l16 == 0) {
      float bd = (z_sq[rz] - 2.0f * s) + e_sq[nn * KCODES + code];
      atomicMin(&winner[rz],
                ((unsigned long long)__float_as_uint(bd) << 32) | (unsigned)code);
    }
  }
}

// ------------------------------------------------------------ passB3 (gather)
// 1024 blocks x 256 thr; wave per 4 rows (ILP-4 chains; 16 waves/CU).
// Loss free from winner's high 32 bits (exact rescored fp32 distance).
// NO fence, NO ticket -- final reduction is a separate kernel.
__global__ __launch_bounds__(256)
void passB3_kernel(const float* __restrict__ emb,
                   const unsigned long long* __restrict__ winner, float* __restrict__ out,
                   int* __restrict__ counts, float* __restrict__ lossarr) {
  __shared__ float lsum[4];
  const int w = threadIdx.x >> 6, lane = threadIdx.x & 63;
  const int gw = blockIdx.x * 4 + w;        // 0..4095
  const int r0 = gw * 4;

  unsigned long long wv[4];
  #pragma unroll
  for (int i = 0; i < 4; ++i) wv[i] = winner[r0 + i];

  float4 ev[4];
  #pragma unroll
  for (int i = 0; i < 4; ++i) {
    int bk = (int)(unsigned)wv[i];
    ev[i] = ((const float4*)(emb + ((size_t)((r0 + i) & 1) * KCODES + bk) * DSUB))[lane];
  }
  #pragma unroll
  for (int i = 0; i < 4; ++i)
    ((float4*)(out + (size_t)(r0 + i) * DSUB))[lane] = ev[i];

  if (lane < 4) {
    int bk = (int)(unsigned)wv[lane];
    out[IDX_OFF + r0 + lane] = (float)bk;
    atomicAdd(&counts[((r0 + lane) & 1) * KCODES + bk], 1);
  }
  if (lane == 0) {
    float ls = 0.f;
    #pragma unroll
    for (int i = 0; i < 4; ++i) ls += __uint_as_float((unsigned)(wv[i] >> 32));
    lsum[w] = ls;
  }
  __syncthreads();
  if (threadIdx.x == 0)
    lossarr[blockIdx.x] = lsum[0] + lsum[1] + lsum[2] + lsum[3];
}

// ------------------------------------------------------------ final kernel
__global__ void final_kernel(const int* __restrict__ counts, const float* __restrict__ lossarr,
                             float* __restrict__ out) {
  __shared__ float redh[256];
  __shared__ float redl[256];
  float h = 0.0f, ls = 0.0f;
  for (int k = threadIdx.x; k < KCODES; k += 256) {
    float p = (float)(counts[k] + counts[KCODES + k]) * (1.0f / 16384.0f);
    h -= p * logf(p + 1e-10f);
  }
  for (int k = threadIdx.x; k < 1024; k += 256) ls += lossarr[k];
  redh[threadIdx.x] = h;
  redl[threadIdx.x] = ls;
  __syncthreads();
  for (int s = 128; s; s >>= 1) {
    if (threadIdx.x < s) {
      redh[threadIdx.x] += redh[threadIdx.x + s];
      redl[threadIdx.x] += redl[threadIdx.x + s];
    }
    __syncthreads();
  }
  if (threadIdx.x == 0) {
    out[LOSS_OFF + 0] = 0.25f * redl[0] * (1.0f / (float)QUANT_N);
    out[LOSS_OFF + 1] = 0.0f;
    out[LOSS_OFF + 2] = expf(redh[0]);
  }
}

extern "C" void kernel_launch(void* const* d_in, const int* in_sizes, int n_in,
                              void* d_out, int out_size, void* d_ws, size_t ws_size,
                              hipStream_t stream) {
  const float* z   = (const float*)d_in[0];
  const float* emb = (const float*)d_in[1];
  float* out = (float*)d_out;
  char*  ws  = (char*)d_ws;

  float* e_sq   = (float*)(ws + WS_ESQ);
  float* z_sq   = (float*)(ws + WS_ZSQ);
  int*   counts = (int*)(ws + WS_COUNTS);
  unsigned long long* winner = (unsigned long long*)(ws + WS_WINNER);
  float* lossarr = (float*)(ws + WS_LOSSARR);
  unsigned short* zbf = (unsigned short*)(ws + WS_ZBF);
  unsigned short* ebf = (unsigned short*)(ws + WS_EBF);
  unsigned* tm32 = (unsigned*)(ws + WS_TM);

  prep_kernel<<<512, 256, 0, stream>>>(z, emb, e_sq, z_sq, zbf, ebf, counts, winner);
  for (int c = 0; c < 2; ++c) {
    dim3 gA(32, 8, 2);
    passA_kernel<<<gA, 256, 0, stream>>>(zbf, ebf, e_sq, tm32, c * 4096);
    passB12_kernel<<<1024, 256, 0, stream>>>(tm32, z, emb, e_sq, z_sq, winner, c * 8192);
  }
  passB3_kernel<<<1024, 256, 0, stream>>>(emb, winner, out, counts, lossarr);
  final_kernel<<<1, 256, 0, stream>>>(counts, lossarr, out);
}